// Round 6
// baseline (140.783 us; speedup 1.0000x reference)
//
#include <hip/hip_runtime.h>

// SemanticConditioner: out = canvas + (embeddings @ W^T + residuals)[region_ids]
// B=4, N=65536, D=256, E=1536, R=512  (all fp32)

#define B_DIM 4
#define N_DIM 65536
#define D_DIM 256
#define E_DIM 1536
#define R_DIM 512
#define RPB   4     // embedding rows per block (cond GEMM)
#define KS    4     // K-splits (cond GEMM)
#define KSUB  (E_DIM / KS)      // 384
#define KSUB4 (KSUB / 4)        // 96

typedef float f32x4 __attribute__((ext_vector_type(4)));

// ---------------------------------------------------------------------------
// Kernel 1: transpose W [D][E] -> Wt [E][D]
// grid (E/32, D/32) = (48, 8), 256 threads
// ---------------------------------------------------------------------------
__global__ __launch_bounds__(256) void k_transpose(const float* __restrict__ W,
                                                   float* __restrict__ Wt) {
    __shared__ float t[32][33];
    const int eb = blockIdx.x * 32;
    const int db = blockIdx.y * 32;
    const int tx = threadIdx.x & 31;
    const int ty = threadIdx.x >> 5;
#pragma unroll
    for (int j = 0; j < 4; ++j)
        t[ty + 8 * j][tx] = W[(size_t)(db + ty + 8 * j) * E_DIM + eb + tx];
    __syncthreads();
#pragma unroll
    for (int j = 0; j < 4; ++j)
        Wt[(size_t)(eb + ty + 8 * j) * D_DIM + db + tx] = t[tx][ty + 8 * j];
}

// ---------------------------------------------------------------------------
// Kernel 2: partial GEMM  part[ks][r][d] = sum_{e in ks-chunk} emb[r][e]*Wt[e][d]
// grid (R/RPB, KS) = (128, 4) = 512 blocks (2/CU), 256 threads
// ---------------------------------------------------------------------------
__global__ __launch_bounds__(256) void k_cond_part(const float* __restrict__ emb,
                                                   const float* __restrict__ Wt,
                                                   float* __restrict__ part) {
    __shared__ f32x4 embs[RPB][KSUB4];  // 6 KB
    const int r0 = blockIdx.x * RPB;
    const int ks = blockIdx.y;
    const int d  = threadIdx.x;

    const f32x4* eg = reinterpret_cast<const f32x4*>(emb);
    for (int f = d; f < RPB * KSUB4; f += 256) {
        const int rr = f / KSUB4, gg = f % KSUB4;
        embs[rr][gg] = eg[(size_t)(r0 + rr) * (E_DIM / 4) + ks * KSUB4 + gg];
    }
    __syncthreads();

    float acc0 = 0.f, acc1 = 0.f, acc2 = 0.f, acc3 = 0.f;
    const int ebase = ks * KSUB;
#pragma unroll 8
    for (int g = 0; g < KSUB4; ++g) {
        const f32x4 a0 = embs[0][g];
        const f32x4 a1 = embs[1][g];
        const f32x4 a2 = embs[2][g];
        const f32x4 a3 = embs[3][g];
        const int e = ebase + 4 * g;
        const float w0 = Wt[(size_t)(e + 0) * D_DIM + d];
        const float w1 = Wt[(size_t)(e + 1) * D_DIM + d];
        const float w2 = Wt[(size_t)(e + 2) * D_DIM + d];
        const float w3 = Wt[(size_t)(e + 3) * D_DIM + d];
        acc0 += a0.x * w0 + a0.y * w1 + a0.z * w2 + a0.w * w3;
        acc1 += a1.x * w0 + a1.y * w1 + a1.z * w2 + a1.w * w3;
        acc2 += a2.x * w0 + a2.y * w1 + a2.z * w2 + a2.w * w3;
        acc3 += a3.x * w0 + a3.y * w1 + a3.z * w2 + a3.w * w3;
    }
    float* p = part + ((size_t)ks * R_DIM + r0) * D_DIM + d;
    p[0 * D_DIM] = acc0;
    p[1 * D_DIM] = acc1;
    p[2 * D_DIM] = acc2;
    p[3 * D_DIM] = acc3;
}

// ---------------------------------------------------------------------------
// Kernel 3: cond[r][d] = sum_ks part[ks][r][d] + res[r][d]
// grid R*D/256 = 512 blocks, 256 threads
// ---------------------------------------------------------------------------
__global__ __launch_bounds__(256) void k_reduce(const float* __restrict__ part,
                                                const float* __restrict__ res,
                                                float* __restrict__ cond) {
    const int i = blockIdx.x * 256 + threadIdx.x;  // r*D + d
    const size_t stride = (size_t)R_DIM * D_DIM;
    cond[i] = part[i] + part[i + stride] + part[i + 2 * stride] +
              part[i + 3 * stride] + res[i];
}

// ---------------------------------------------------------------------------
// Kernel 4: out = canvas + cond[region_ids]   (512 MB memory-bound pass)
// b-fused (one rid + one cond row per wave serve all B=4 batch rows).
// A/B this round: NT hints REMOVED — plain cached loads/stores, matching the
// path the 7 TB/s fills and 6.3 TB/s copy ceiling use.
// grid 2048 x 256, 8 iterations x 4 batches = 32 float4/thread.
// ---------------------------------------------------------------------------
__global__ __launch_bounds__(256) void k_add(const f32x4* __restrict__ canvas,
                                             const int* __restrict__ rid,
                                             const f32x4* __restrict__ cond,
                                             f32x4* __restrict__ out) {
    const int stride = gridDim.x * blockDim.x;              // 524,288
    const int bstep  = N_DIM * (D_DIM / 4);                 // 4,194,304 float4
    int i = blockIdx.x * blockDim.x + threadIdx.x;          // n*64 + d4
    // N*D/4 = 4,194,304 = 8 * stride (exact)
#pragma unroll 1
    for (int it = 0; it < 8; ++it, i += stride) {
        const f32x4 c0 = canvas[i];
        const f32x4 c1 = canvas[i + bstep];
        const f32x4 c2 = canvas[i + 2 * bstep];
        const f32x4 c3 = canvas[i + 3 * bstep];
        const int n  = i >> 6;          // wave-uniform
        const int d4 = i & 63;
        const int r  = rid[n];          // wave-uniform, L1/L2
        const f32x4 a = cond[r * (D_DIM / 4) + d4];  // coalesced 1 KB row, L2
        out[i]             = c0 + a;
        out[i + bstep]     = c1 + a;
        out[i + 2 * bstep] = c2 + a;
        out[i + 3 * bstep] = c3 + a;
    }
}

// ---------------------------------------------------------------------------
extern "C" void kernel_launch(void* const* d_in, const int* in_sizes, int n_in,
                              void* d_out, int out_size, void* d_ws, size_t ws_size,
                              hipStream_t stream) {
    const float* canvas = (const float*)d_in[0];  // [B,N,D]
    const float* emb    = (const float*)d_in[1];  // [R,E]
    const float* W      = (const float*)d_in[2];  // [D,E]
    const float* res    = (const float*)d_in[3];  // [R,D]
    const int*   rid    = (const int*)d_in[4];    // [N]

    // ws layout: Wt (E*D) | part (KS*R*D) | cond (R*D)   -- all fp32
    float* Wt   = (float*)d_ws;
    float* part = Wt + (size_t)E_DIM * D_DIM;
    float* cond = part + (size_t)KS * R_DIM * D_DIM;

    dim3 tgrid(E_DIM / 32, D_DIM / 32);
    k_transpose<<<tgrid, 256, 0, stream>>>(W, Wt);
    dim3 cgrid(R_DIM / RPB, KS);
    k_cond_part<<<cgrid, 256, 0, stream>>>(emb, Wt, part);
    k_reduce<<<(R_DIM * D_DIM) / 256, 256, 0, stream>>>(part, res, cond);
    k_add<<<2048, 256, 0, stream>>>((const f32x4*)canvas, rid,
                                    (const f32x4*)cond, (f32x4*)d_out);
}

// Round 7
// 130.927 us; speedup vs baseline: 1.0753x; 1.0753x over previous
//
#include <hip/hip_runtime.h>

// SemanticConditioner: out = canvas + (embeddings @ W^T + residuals)[region_ids]
// B=4, N=65536, D=256, E=1536, R=512  (all fp32)

#define B_DIM 4
#define N_DIM 65536
#define D_DIM 256
#define E_DIM 1536
#define R_DIM 512
#define RPB   4     // embedding rows per block (cond GEMM)
#define KS    4     // K-splits (cond GEMM)
#define KSUB  (E_DIM / KS)      // 384
#define KSUB4 (KSUB / 4)        // 96

typedef float f32x4 __attribute__((ext_vector_type(4)));

// ---------------------------------------------------------------------------
// Kernel 1: transpose W [D][E] -> Wt [E][D]
// grid (E/32, D/32) = (48, 8), 256 threads
// ---------------------------------------------------------------------------
__global__ __launch_bounds__(256) void k_transpose(const float* __restrict__ W,
                                                   float* __restrict__ Wt) {
    __shared__ float t[32][33];
    const int eb = blockIdx.x * 32;
    const int db = blockIdx.y * 32;
    const int tx = threadIdx.x & 31;
    const int ty = threadIdx.x >> 5;
#pragma unroll
    for (int j = 0; j < 4; ++j)
        t[ty + 8 * j][tx] = W[(size_t)(db + ty + 8 * j) * E_DIM + eb + tx];
    __syncthreads();
#pragma unroll
    for (int j = 0; j < 4; ++j)
        Wt[(size_t)(eb + ty + 8 * j) * D_DIM + db + tx] = t[tx][ty + 8 * j];
}

// ---------------------------------------------------------------------------
// Kernel 2: partial GEMM  part[ks][r][d] = sum_{e in ks-chunk} emb[r][e]*Wt[e][d]
// grid (R/RPB, KS) = (128, 4) = 512 blocks (2/CU), 256 threads
// ---------------------------------------------------------------------------
__global__ __launch_bounds__(256) void k_cond_part(const float* __restrict__ emb,
                                                   const float* __restrict__ Wt,
                                                   float* __restrict__ part) {
    __shared__ f32x4 embs[RPB][KSUB4];  // 6 KB
    const int r0 = blockIdx.x * RPB;
    const int ks = blockIdx.y;
    const int d  = threadIdx.x;

    const f32x4* eg = reinterpret_cast<const f32x4*>(emb);
    for (int f = d; f < RPB * KSUB4; f += 256) {
        const int rr = f / KSUB4, gg = f % KSUB4;
        embs[rr][gg] = eg[(size_t)(r0 + rr) * (E_DIM / 4) + ks * KSUB4 + gg];
    }
    __syncthreads();

    float acc0 = 0.f, acc1 = 0.f, acc2 = 0.f, acc3 = 0.f;
    const int ebase = ks * KSUB;
#pragma unroll 8
    for (int g = 0; g < KSUB4; ++g) {
        const f32x4 a0 = embs[0][g];
        const f32x4 a1 = embs[1][g];
        const f32x4 a2 = embs[2][g];
        const f32x4 a3 = embs[3][g];
        const int e = ebase + 4 * g;
        const float w0 = Wt[(size_t)(e + 0) * D_DIM + d];
        const float w1 = Wt[(size_t)(e + 1) * D_DIM + d];
        const float w2 = Wt[(size_t)(e + 2) * D_DIM + d];
        const float w3 = Wt[(size_t)(e + 3) * D_DIM + d];
        acc0 += a0.x * w0 + a0.y * w1 + a0.z * w2 + a0.w * w3;
        acc1 += a1.x * w0 + a1.y * w1 + a1.z * w2 + a1.w * w3;
        acc2 += a2.x * w0 + a2.y * w1 + a2.z * w2 + a2.w * w3;
        acc3 += a3.x * w0 + a3.y * w1 + a3.z * w2 + a3.w * w3;
    }
    float* p = part + ((size_t)ks * R_DIM + r0) * D_DIM + d;
    p[0 * D_DIM] = acc0;
    p[1 * D_DIM] = acc1;
    p[2 * D_DIM] = acc2;
    p[3 * D_DIM] = acc3;
}

// ---------------------------------------------------------------------------
// Kernel 3: cond[r][d] = sum_ks part[ks][r][d] + res[r][d]
// grid R*D/256 = 512 blocks, 256 threads
// ---------------------------------------------------------------------------
__global__ __launch_bounds__(256) void k_reduce(const float* __restrict__ part,
                                                const float* __restrict__ res,
                                                float* __restrict__ cond) {
    const int i = blockIdx.x * 256 + threadIdx.x;  // r*D + d
    const size_t stride = (size_t)R_DIM * D_DIM;
    cond[i] = part[i] + part[i + stride] + part[i + 2 * stride] +
              part[i + 3 * stride] + res[i];
}

// ---------------------------------------------------------------------------
// Kernel 4: out = canvas + cond[region_ids]   (512 MB memory-bound pass)
// A/B this round: CACHED canvas loads (allocate in the 256 MB Infinity Cache,
// stay resident across graph replays) + NT stores for out (LLC no-allocate,
// don't evict canvas). Steady-state replay: canvas from L3, out to HBM.
// b-fused: one rid + one cond row per wave serve all B=4 batch rows.
// grid 2048 x 256, 8 iterations x 4 batches = 32 float4/thread.
// ---------------------------------------------------------------------------
__global__ __launch_bounds__(256) void k_add(const f32x4* __restrict__ canvas,
                                             const int* __restrict__ rid,
                                             const f32x4* __restrict__ cond,
                                             f32x4* __restrict__ out) {
    const int stride = gridDim.x * blockDim.x;              // 524,288
    const int bstep  = N_DIM * (D_DIM / 4);                 // 4,194,304 float4
    int i = blockIdx.x * blockDim.x + threadIdx.x;          // n*64 + d4
    // N*D/4 = 4,194,304 = 8 * stride (exact)
#pragma unroll 1
    for (int it = 0; it < 8; ++it, i += stride) {
        const f32x4 c0 = canvas[i];
        const f32x4 c1 = canvas[i + bstep];
        const f32x4 c2 = canvas[i + 2 * bstep];
        const f32x4 c3 = canvas[i + 3 * bstep];
        const int n  = i >> 6;          // wave-uniform
        const int d4 = i & 63;
        const int r  = rid[n];          // wave-uniform, L1/L2
        const f32x4 a = cond[r * (D_DIM / 4) + d4];  // coalesced 1 KB row, L2
        __builtin_nontemporal_store(c0 + a, &out[i]);
        __builtin_nontemporal_store(c1 + a, &out[i + bstep]);
        __builtin_nontemporal_store(c2 + a, &out[i + 2 * bstep]);
        __builtin_nontemporal_store(c3 + a, &out[i + 3 * bstep]);
    }
}

// ---------------------------------------------------------------------------
extern "C" void kernel_launch(void* const* d_in, const int* in_sizes, int n_in,
                              void* d_out, int out_size, void* d_ws, size_t ws_size,
                              hipStream_t stream) {
    const float* canvas = (const float*)d_in[0];  // [B,N,D]
    const float* emb    = (const float*)d_in[1];  // [R,E]
    const float* W      = (const float*)d_in[2];  // [D,E]
    const float* res    = (const float*)d_in[3];  // [R,D]
    const int*   rid    = (const int*)d_in[4];    // [N]

    // ws layout: Wt (E*D) | part (KS*R*D) | cond (R*D)   -- all fp32
    float* Wt   = (float*)d_ws;
    float* part = Wt + (size_t)E_DIM * D_DIM;
    float* cond = part + (size_t)KS * R_DIM * D_DIM;

    dim3 tgrid(E_DIM / 32, D_DIM / 32);
    k_transpose<<<tgrid, 256, 0, stream>>>(W, Wt);
    dim3 cgrid(R_DIM / RPB, KS);
    k_cond_part<<<cgrid, 256, 0, stream>>>(emb, Wt, part);
    k_reduce<<<(R_DIM * D_DIM) / 256, 256, 0, stream>>>(part, res, cond);
    k_add<<<2048, 256, 0, stream>>>((const f32x4*)canvas, rid,
                                    (const f32x4*)cond, (f32x4*)d_out);
}